// Round 5
// baseline (366.732 us; speedup 1.0000x reference)
//
#include <hip/hip_runtime.h>
#include <hip/hip_cooperative_groups.h>
#include <math.h>

namespace cg = cooperative_groups;

#define L 2048
#define BATCH 8
#define NS2 64                  // slabs per batch in fused path (32 rows each)
#define GRID2 (BATCH * NS2)     // 512 blocks -> 2 per CU, trivially co-resident
#define RPS 16                  // fallback: rows per block
#define NSPLIT (L / RPS)        // fallback: 128 slabs per batch
#define EPSF 1e-8f
#define C2 2.885390081777927f   // 2/ln2 : exp(2x) = exp2(x*C2)
#define C4 5.770780163555854f   // 4/ln2 : exp(4x) = exp2(x*C4)

typedef float f32x4 __attribute__((ext_vector_type(4)));

__device__ __forceinline__ float fexp2(float x) {
  return __builtin_amdgcn_exp2f(x);   // v_exp_f32
}
__device__ __forceinline__ float fsqrt(float x) {
  return __builtin_amdgcn_sqrtf(x);   // v_sqrt_f32 (~1.5 ulp)
}

// ---------------- fused cooperative kernel ----------------
// 512 blocks x 256 threads (2 blocks/CU: 8 waves, 64KB LDS -> far under the
// 32-wave / 160KB limits, so cooperative residency check cannot fail).
// Block bid = b*64 + sb owns rows [sb*32, sb*32+32) of batch b in phases A and
// C; wave w owns rows sb*32 + w*8 .. +7. Per-row 1/rowsum survives the grid
// syncs in registers (all 64 lanes hold the butterfly-reduced sum).
__global__ __launch_bounds__(256, 2) void fused_k(
    const float* __restrict__ sim, const int* __restrict__ lengths,
    float* __restrict__ pcol, float* __restrict__ cinv,
    float* __restrict__ out) {
  const int bid = blockIdx.x;
  const int b = bid >> 6;
  const int sb = bid & 63;
  const int len0 = lengths[2 * b], len1 = lengths[2 * b + 1];
  const int tid = threadIdx.x;
  const int wave = tid >> 6, lane = tid & 63;
  const int i0w = sb * 32 + wave * 8;
  const int jb = lane * 4;
  const int nrow = min(8, len0 - i0w);   // may be <= 0: all 8 rows masked

  __shared__ float cpart[4][2048];       // 32 KB; reused in phases B and C

  // ---------- Phase A: row sums + 32-row column partials ----------
  float4 cacc[8];
#pragma unroll
  for (int s = 0; s < 8; ++s) cacc[s] = make_float4(0.f, 0.f, 0.f, 0.f);
  float racc[8] = {0.f, 0.f, 0.f, 0.f, 0.f, 0.f, 0.f, 0.f};

#pragma unroll
  for (int r = 0; r < 8; ++r) {
    if (r < nrow) {                      // wave-uniform
      const float* p = sim + ((size_t)b * L + (i0w + r)) * L + jb;
      float acc = 0.f;
#pragma unroll
      for (int s = 0; s < 8; ++s) {
        float4 v = *reinterpret_cast<const float4*>(p + s * 256);
        float4 e;
        e.x = fexp2(v.x * C2); e.y = fexp2(v.y * C2);
        e.z = fexp2(v.z * C2); e.w = fexp2(v.w * C2);
        if (s >= 4) {                    // len1 >= 1024: steps 0-3 always valid
          const int j = s * 256 + jb;
          if (j + 0 >= len1) e.x = 0.f;
          if (j + 1 >= len1) e.y = 0.f;
          if (j + 2 >= len1) e.z = 0.f;
          if (j + 3 >= len1) e.w = 0.f;
        }
        acc += (e.x + e.y) + (e.z + e.w);
        cacc[s].x += e.x; cacc[s].y += e.y; cacc[s].z += e.z; cacc[s].w += e.w;
      }
      racc[r] = acc;
    }
  }

  // Deferred butterflies (8 overlap); every lane keeps 1/rowsum in a register.
  float rinv_r[8];
#pragma unroll
  for (int r = 0; r < 8; ++r) {
    float v = racc[r];
#pragma unroll
    for (int off = 1; off < 64; off <<= 1) v += __shfl_xor(v, off, 64);
    rinv_r[r] = 1.0f / v;                // inf for masked rows: never used
  }

  // merge the 4 waves' column partials -> one pcol slab per block
#pragma unroll
  for (int s = 0; s < 8; ++s)
    *reinterpret_cast<float4*>(&cpart[wave][s * 256 + jb]) = cacc[s];
  __syncthreads();

#pragma unroll
  for (int h = 0; h < 2; ++h) {
    const int c = h * 1024 + tid * 4;
    float4 a0 = *reinterpret_cast<const float4*>(&cpart[0][c]);
    float4 a1 = *reinterpret_cast<const float4*>(&cpart[1][c]);
    float4 a2 = *reinterpret_cast<const float4*>(&cpart[2][c]);
    float4 a3 = *reinterpret_cast<const float4*>(&cpart[3][c]);
    float4 o;
    o.x = (a0.x + a1.x) + (a2.x + a3.x);
    o.y = (a0.y + a1.y) + (a2.y + a3.y);
    o.z = (a0.z + a1.z) + (a2.z + a3.z);
    o.w = (a0.w + a1.w) + (a2.w + a3.w);
    *reinterpret_cast<float4*>(&pcol[(size_t)(b * NS2 + sb) * L + c]) = o;
  }

  cg::this_grid().sync();

  // ---------- Phase B: merge 64 slabs -> cinv (32 cols per block) ----------
  {
    const int colbase = bid * 32;        // = b*2048 + sb*32
    const int b2 = colbase >> 11;
    const int j2 = (colbase & (L - 1)) + (tid & 31);
    const int g = tid >> 5;              // 8 groups of 32 threads
    const float* p = pcol + ((size_t)b2 * NS2 + g * 8) * L + j2;
    float s = 0.f;
#pragma unroll
    for (int c = 0; c < 8; ++c) s += p[(size_t)c * L];
    cpart[0][tid] = s;                   // [group][col] flattened (g*32 + col)
    __syncthreads();
    if (tid < 32) {
      float t = 0.f;
#pragma unroll
      for (int gg = 0; gg < 8; ++gg) t += cpart[0][gg * 32 + tid];
      cinv[colbase + tid] = 1.0f / t;    // inf for j >= len1: masked in phase C
    }
  }

  cg::this_grid().sync();

  // ---------- Phase C: finalize the block's own 32 rows ----------
  // Stage this batch's cinv row (8KB) into LDS once; 32 row-passes read LDS
  // instead of re-fetching through a thrashing L1.
#pragma unroll
  for (int q = 0; q < 2; ++q)
    cpart[0][q * 1024 + tid * 4 + 0 + 0] = 0.f;  // placeholder overwritten below
  {
#pragma unroll
    for (int q = 0; q < 2; ++q) {
      const int c = q * 1024 + tid * 4;
      *reinterpret_cast<float4*>(&cpart[0][c]) =
          *reinterpret_cast<const float4*>(cinv + (b << 11) + c);
    }
  }
  __syncthreads();

#pragma unroll
  for (int r = 0; r < 8; ++r) {
    const int i = i0w + r;
    const size_t off = ((size_t)b * L + i) * L + jb;
    if (r < nrow) {                      // wave-uniform
      const float ri = rinv_r[r];
#pragma unroll
      for (int s = 0; s < 8; ++s) {
        const int j = s * 256 + jb;
        f32x4 v = *reinterpret_cast<const f32x4*>(sim + off + s * 256);
        float4 ci = *reinterpret_cast<const float4*>(&cpart[0][j]);
        f32x4 o;
        o.x = (j + 0 < len1) ? fsqrt(EPSF + fexp2(v.x * C4) * ri * ci.x) : 0.f;
        o.y = (j + 1 < len1) ? fsqrt(EPSF + fexp2(v.y * C4) * ri * ci.y) : 0.f;
        o.z = (j + 2 < len1) ? fsqrt(EPSF + fexp2(v.z * C4) * ri * ci.z) : 0.f;
        o.w = (j + 3 < len1) ? fsqrt(EPSF + fexp2(v.w * C4) * ri * ci.w) : 0.f;
        __builtin_nontemporal_store(
            o, reinterpret_cast<f32x4*>(out + off + s * 256));
      }
    } else {                             // masked row: still write zeros
      const f32x4 z = (f32x4){0.f, 0.f, 0.f, 0.f};
#pragma unroll
      for (int s = 0; s < 8; ++s)
        __builtin_nontemporal_store(
            z, reinterpret_cast<f32x4*>(out + off + s * 256));
    }
  }
}

// ---------------- fallback path (verified at 248 us) ----------------
__global__ __launch_bounds__(256) void stats_k(
    const float* __restrict__ sim, const int* __restrict__ lengths,
    float* __restrict__ rinv, float* __restrict__ pcol) {
  const int b = blockIdx.y;
  const int islab = blockIdx.x;
  const int len0 = lengths[2 * b], len1 = lengths[2 * b + 1];
  const int tid = threadIdx.x;
  const int wave = tid >> 6, lane = tid & 63;
  const int i0 = islab * RPS + wave * 4;
  const int jb = lane * 4;
  const int nrow = min(4, len0 - i0);

  float4 cacc[8];
#pragma unroll
  for (int s = 0; s < 8; ++s) cacc[s] = make_float4(0.f, 0.f, 0.f, 0.f);
  float racc[4] = {0.f, 0.f, 0.f, 0.f};

#pragma unroll
  for (int r = 0; r < 4; ++r) {
    if (r < nrow) {
      const float* p = sim + ((size_t)b * L + (i0 + r)) * L + jb;
      float acc = 0.f;
#pragma unroll
      for (int s = 0; s < 8; ++s) {
        float4 v = *reinterpret_cast<const float4*>(p + s * 256);
        float4 e;
        e.x = fexp2(v.x * C2); e.y = fexp2(v.y * C2);
        e.z = fexp2(v.z * C2); e.w = fexp2(v.w * C2);
        if (s >= 4) {
          const int j = s * 256 + jb;
          if (j + 0 >= len1) e.x = 0.f;
          if (j + 1 >= len1) e.y = 0.f;
          if (j + 2 >= len1) e.z = 0.f;
          if (j + 3 >= len1) e.w = 0.f;
        }
        acc += (e.x + e.y) + (e.z + e.w);
        cacc[s].x += e.x; cacc[s].y += e.y; cacc[s].z += e.z; cacc[s].w += e.w;
      }
      racc[r] = acc;
    }
  }
#pragma unroll
  for (int r = 0; r < 4; ++r) {
    if (r < nrow) {
      float v = racc[r];
#pragma unroll
      for (int off = 1; off < 64; off <<= 1) v += __shfl_xor(v, off, 64);
      if (lane == 0) rinv[(size_t)b * L + (i0 + r)] = 1.0f / v;
    }
  }

  __shared__ float cpart[4][2048];
#pragma unroll
  for (int s = 0; s < 8; ++s)
    *reinterpret_cast<float4*>(&cpart[wave][s * 256 + jb]) = cacc[s];
  __syncthreads();

#pragma unroll
  for (int h = 0; h < 2; ++h) {
    const int c = h * 1024 + tid * 4;
    float4 a0 = *reinterpret_cast<const float4*>(&cpart[0][c]);
    float4 a1 = *reinterpret_cast<const float4*>(&cpart[1][c]);
    float4 a2 = *reinterpret_cast<const float4*>(&cpart[2][c]);
    float4 a3 = *reinterpret_cast<const float4*>(&cpart[3][c]);
    float4 o;
    o.x = (a0.x + a1.x) + (a2.x + a3.x);
    o.y = (a0.y + a1.y) + (a2.y + a3.y);
    o.z = (a0.z + a1.z) + (a2.z + a3.z);
    o.w = (a0.w + a1.w) + (a2.w + a3.w);
    *reinterpret_cast<float4*>(&pcol[(size_t)(b * NSPLIT + islab) * L + c]) = o;
  }
}

__global__ __launch_bounds__(128) void col_merge_k(
    const float* __restrict__ pcol, float* __restrict__ cinv) {
  const int idx = blockIdx.x * 128 + threadIdx.x;  // b*L + j
  const int b = idx >> 11, j = idx & (L - 1);
  const float* p = pcol + (size_t)b * NSPLIT * L + j;
  float s = 0.f;
#pragma unroll 16
  for (int c = 0; c < NSPLIT; ++c) s += p[(size_t)c * L];
  cinv[idx] = 1.0f / s;
}

__global__ __launch_bounds__(512) void finalize_k(
    const float* __restrict__ sim, const int* __restrict__ lengths,
    const float* __restrict__ rinv, const float* __restrict__ cinv,
    float* __restrict__ out) {
  const int row = blockIdx.x;
  const int b = row >> 11, i = row & (L - 1);
  const int len0 = lengths[2 * b], len1 = lengths[2 * b + 1];
  const int j = threadIdx.x * 4;
  const size_t off = (size_t)row * L + j;
  f32x4 o;
  if (i >= len0) {
    o = (f32x4){0.f, 0.f, 0.f, 0.f};
  } else {
    const float ri = rinv[row];
    f32x4 v = __builtin_nontemporal_load(
        reinterpret_cast<const f32x4*>(sim + off));
    f32x4 ci = *reinterpret_cast<const f32x4*>(cinv + ((size_t)b << 11) + j);
    o.x = (j + 0 < len1) ? fsqrt(EPSF + fexp2(v.x * C4) * ri * ci.x) : 0.f;
    o.y = (j + 1 < len1) ? fsqrt(EPSF + fexp2(v.y * C4) * ri * ci.y) : 0.f;
    o.z = (j + 2 < len1) ? fsqrt(EPSF + fexp2(v.z * C4) * ri * ci.z) : 0.f;
    o.w = (j + 3 < len1) ? fsqrt(EPSF + fexp2(v.w * C4) * ri * ci.w) : 0.f;
  }
  __builtin_nontemporal_store(o, reinterpret_cast<f32x4*>(out + off));
}

extern "C" void kernel_launch(void* const* d_in, const int* in_sizes, int n_in,
                              void* d_out, int out_size, void* d_ws, size_t ws_size,
                              hipStream_t stream) {
  const float* sim = (const float*)d_in[0];
  const int* lengths = (const int*)d_in[1];
  float* out = (float*)d_out;
  float* ws = (float*)d_ws;

  const int NR = BATCH * L;  // 16384
  float* rinv = ws;                         // fallback only
  float* cinv = ws + NR;
  float* pcol = ws + 2 * (size_t)NR;        // 8 MiB region (both layouts fit)

  void* args[] = {(void*)&sim, (void*)&lengths, (void*)&pcol,
                  (void*)&cinv, (void*)&out};
  hipError_t err = hipLaunchCooperativeKernel(
      (const void*)fused_k, dim3(GRID2), dim3(256), args, 0, stream);
  if (err != hipSuccess) {
    // capacity/capture surprise: run the verified 3-kernel path instead
    hipLaunchKernelGGL(stats_k, dim3(NSPLIT, BATCH), dim3(256), 0, stream,
                       sim, lengths, rinv, pcol);
    hipLaunchKernelGGL(col_merge_k, dim3(NR / 128), dim3(128), 0, stream,
                       pcol, cinv);
    hipLaunchKernelGGL(finalize_k, dim3(NR), dim3(512), 0, stream,
                       sim, lengths, rinv, cinv, out);
  }
}

// Round 9
// 280.599 us; speedup vs baseline: 1.3070x; 1.3070x over previous
//
#include <hip/hip_runtime.h>
#include <math.h>

#define L 2048
#define BATCH 8
#define RPS 16               // rows per block in stats kernel (4 waves x 4 rows)
#define NSPLIT (L / RPS)     // 128 column-partial slabs per batch
#define EPSF 1e-8f
#define C2 2.885390081777927f   // 2/ln2 : exp(2x) = exp2(x*C2)
#define C4 5.770780163555854f   // 4/ln2 : exp(4x) = exp2(x*C4)

typedef float f32x4 __attribute__((ext_vector_type(4)));

__device__ __forceinline__ float fexp2(float x) {
  return __builtin_amdgcn_exp2f(x);   // v_exp_f32
}
__device__ __forceinline__ float fsqrt(float x) {
  return __builtin_amdgcn_sqrtf(x);   // v_sqrt_f32 (~1.5 ulp)
}

// 256 threads (4 waves); wave w owns rows i0+4w..+3. Round-5 counters showed
// VGPR=48 -> ~0.6 loads in flight/wave -> 16% HBM. Fix: (256,4) raises the
// VGPR cap to 128 (matches the LDS-capped 4 blocks/CU = 16 waves/CU), and an
// explicit two-row register pipeline issues row r+1's 8 float4 loads into a
// second buffer BEFORE row r's exp/accumulate executes. Branchless row stream:
// clamped row pointer + 0/1 mask multiplier (masked rows load a valid clamped
// row and contribute zero), so no branch blocks load hoisting.
__global__ __launch_bounds__(256, 4) void stats_k(
    const float* __restrict__ sim, const int* __restrict__ lengths,
    float* __restrict__ rinv, float* __restrict__ pcol) {
  const int b = blockIdx.y;
  const int islab = blockIdx.x;
  const int len0 = lengths[2 * b], len1 = lengths[2 * b + 1];
  const int tid = threadIdx.x;
  const int wave = tid >> 6, lane = tid & 63;
  const int i0 = islab * RPS + wave * 4;
  const int jb = lane * 4;
  const int nrow = min(4, len0 - i0);    // may be <= 0: whole wave masked

  float4 cacc[8];
#pragma unroll
  for (int s = 0; s < 8; ++s) cacc[s] = make_float4(0.f, 0.f, 0.f, 0.f);
  float racc[4] = {0.f, 0.f, 0.f, 0.f};

  if (nrow > 0) {                        // wave-uniform
    const float* base = sim + ((size_t)b * L + i0) * L + jb;
    // clamped row offset: rows >= nrow re-load row nrow-1 (valid), masked to 0
    float4 bufA[8], bufB[8];
    {
      const float* p = base;             // row 0 always valid here
#pragma unroll
      for (int s = 0; s < 8; ++s)
        bufA[s] = *reinterpret_cast<const float4*>(p + s * 256);
    }
#pragma unroll
    for (int r = 0; r < 4; ++r) {
      float4* cur = (r & 1) ? bufB : bufA;
      float4* nxt = (r & 1) ? bufA : bufB;
      if (r < 3) {                       // prefetch next row (clamped)
        const int rn = min(r + 1, nrow - 1);
        const float* p = base + (size_t)rn * L;
#pragma unroll
        for (int s = 0; s < 8; ++s)
          nxt[s] = *reinterpret_cast<const float4*>(p + s * 256);
      }
      const float m = (r < nrow) ? 1.f : 0.f;
      float acc = 0.f;
#pragma unroll
      for (int s = 0; s < 8; ++s) {
        float4 v = cur[s];
        float4 e;
        e.x = fexp2(v.x * C2); e.y = fexp2(v.y * C2);
        e.z = fexp2(v.z * C2); e.w = fexp2(v.w * C2);
        if (s >= 4) {                    // len1 >= 1024: steps 0-3 always valid
          const int j = s * 256 + jb;
          if (j + 0 >= len1) e.x = 0.f;
          if (j + 1 >= len1) e.y = 0.f;
          if (j + 2 >= len1) e.z = 0.f;
          if (j + 3 >= len1) e.w = 0.f;
        }
        e.x *= m; e.y *= m; e.z *= m; e.w *= m;
        acc += (e.x + e.y) + (e.z + e.w);
        cacc[s].x += e.x; cacc[s].y += e.y; cacc[s].z += e.z; cacc[s].w += e.w;
      }
      racc[r] = acc;                     // 0 for masked rows
    }
  }

  // Deferred butterflies (4 chains overlap); lane0 writes valid rows only.
#pragma unroll
  for (int r = 0; r < 4; ++r) {
    float v = racc[r];
#pragma unroll
    for (int off = 1; off < 64; off <<= 1) v += __shfl_xor(v, off, 64);
    if (lane == 0 && r < nrow) rinv[(size_t)b * L + (i0 + r)] = 1.0f / v;
  }

  __shared__ float cpart[4][2048];       // 32 KB
#pragma unroll
  for (int s = 0; s < 8; ++s)
    *reinterpret_cast<float4*>(&cpart[wave][s * 256 + jb]) = cacc[s];
  __syncthreads();

#pragma unroll
  for (int h = 0; h < 2; ++h) {
    const int c = h * 1024 + tid * 4;
    float4 a0 = *reinterpret_cast<const float4*>(&cpart[0][c]);
    float4 a1 = *reinterpret_cast<const float4*>(&cpart[1][c]);
    float4 a2 = *reinterpret_cast<const float4*>(&cpart[2][c]);
    float4 a3 = *reinterpret_cast<const float4*>(&cpart[3][c]);
    f32x4 o;
    o.x = (a0.x + a1.x) + (a2.x + a3.x);
    o.y = (a0.y + a1.y) + (a2.y + a3.y);
    o.z = (a0.z + a1.z) + (a2.z + a3.z);
    o.w = (a0.w + a1.w) + (a2.w + a3.w);
    __builtin_nontemporal_store(
        o, reinterpret_cast<f32x4*>(&pcol[(size_t)(b * NSPLIT + islab) * L + c]));
  }
}

// Verified round-3 structure + dual accumulators (safe ILP tweak).
__global__ __launch_bounds__(128) void col_merge_k(
    const float* __restrict__ pcol, float* __restrict__ cinv) {
  const int idx = blockIdx.x * 128 + threadIdx.x;  // b*L + j
  const int b = idx >> 11, j = idx & (L - 1);
  const float* p = pcol + (size_t)b * NSPLIT * L + j;
  float s0 = 0.f, s1 = 0.f;
#pragma unroll 8
  for (int c = 0; c < NSPLIT; c += 2) {
    s0 += p[(size_t)c * L];
    s1 += p[(size_t)(c + 1) * L];
  }
  cinv[idx] = 1.0f / (s0 + s1);   // inf for j >= len1: masked in finalize
}

// Verified round-3 structure (one block = one row; passed at 248us total).
// NT discipline: sim dead after this read -> NT load; out never re-read ->
// NT store (don't displace sim's L3 lines; sim+out = 268MB > 256MB L3).
__global__ __launch_bounds__(512) void finalize_k(
    const float* __restrict__ sim, const int* __restrict__ lengths,
    const float* __restrict__ rinv, const float* __restrict__ cinv,
    float* __restrict__ out) {
  const int row = blockIdx.x;          // b*L + i ; one block = one full row
  const int b = row >> 11, i = row & (L - 1);
  const int len0 = lengths[2 * b], len1 = lengths[2 * b + 1];
  const int j = threadIdx.x * 4;
  const size_t off = (size_t)row * L + j;
  f32x4 o;
  if (i >= len0) {                     // block-uniform branch: zero row
    o = (f32x4){0.f, 0.f, 0.f, 0.f};
  } else {
    const float ri = rinv[row];
    f32x4 v = __builtin_nontemporal_load(
        reinterpret_cast<const f32x4*>(sim + off));
    f32x4 ci = *reinterpret_cast<const f32x4*>(cinv + ((size_t)b << 11) + j);
    o.x = (j + 0 < len1) ? fsqrt(EPSF + fexp2(v.x * C4) * ri * ci.x) : 0.f;
    o.y = (j + 1 < len1) ? fsqrt(EPSF + fexp2(v.y * C4) * ri * ci.y) : 0.f;
    o.z = (j + 2 < len1) ? fsqrt(EPSF + fexp2(v.z * C4) * ri * ci.z) : 0.f;
    o.w = (j + 3 < len1) ? fsqrt(EPSF + fexp2(v.w * C4) * ri * ci.w) : 0.f;
  }
  __builtin_nontemporal_store(o, reinterpret_cast<f32x4*>(out + off));
}

extern "C" void kernel_launch(void* const* d_in, const int* in_sizes, int n_in,
                              void* d_out, int out_size, void* d_ws, size_t ws_size,
                              hipStream_t stream) {
  const float* sim = (const float*)d_in[0];
  const int* lengths = (const int*)d_in[1];
  float* out = (float*)d_out;
  float* ws = (float*)d_ws;

  const int NR = BATCH * L;  // 16384
  float* rinv = ws;
  float* cinv = ws + NR;
  float* pcol = ws + 2 * (size_t)NR;
  // ws use: 2*16384 + 8*128*2048 floats = ~8.1 MiB

  hipLaunchKernelGGL(stats_k, dim3(NSPLIT, BATCH), dim3(256), 0, stream,
                     sim, lengths, rinv, pcol);
  hipLaunchKernelGGL(col_merge_k, dim3(NR / 128), dim3(128), 0, stream,
                     pcol, cinv);
  hipLaunchKernelGGL(finalize_k, dim3(NR), dim3(512), 0, stream,
                     sim, lengths, rinv, cinv, out);
}

// Round 11
// 266.480 us; speedup vs baseline: 1.3762x; 1.0530x over previous
//
#include <hip/hip_runtime.h>
#include <math.h>

#define L 2048
#define BATCH 8
#define RPS 16               // rows per block in stats kernel (4 waves x 4 rows)
#define NSPLIT (L / RPS)     // 128 column-partial slabs per batch
#define EPSF 1e-8f
#define C2 2.885390081777927f   // 2/ln2 : exp(2x) = exp2(x*C2)
#define C4 5.770780163555854f   // 4/ln2 : exp(4x) = exp2(x*C4)

typedef float f32x4 __attribute__((ext_vector_type(4)));

__device__ __forceinline__ float fexp2(float x) {
  return __builtin_amdgcn_exp2f(x);   // v_exp_f32
}
__device__ __forceinline__ float fsqrt(float x) {
  return __builtin_amdgcn_sqrtf(x);   // v_sqrt_f32 (~1.5 ulp)
}

// 256 threads (4 waves); wave w owns rows i0+4w..+3 (round-3 structure,
// measured 248us total). ONE change vs round 3: amdgpu_waves_per_eu(5,5).
// Rationale: round-5 counters showed the compiler chose VGPR=48 (targeting
// 8+ waves/EU) -> only ~2 float4 loads in flight -> 16% HBM. LDS (32KB/block)
// caps residency at 5 blocks/CU = 20 waves = 5 waves/EU anyway, so targeting
// exactly 5 waves/EU costs ZERO occupancy and raises the VGPR budget to ~102,
// letting the scheduler hoist all 8 row loads (32 VGPRs of buffers) ahead of
// the exp chain. Round-9's hand-built pipeline at cap 128 spilled/regressed;
// this lets the scheduler build the same pipeline within a safe budget.
__global__ __launch_bounds__(256)
__attribute__((amdgpu_waves_per_eu(5, 5))) void stats_k(
    const float* __restrict__ sim, const int* __restrict__ lengths,
    float* __restrict__ rinv, float* __restrict__ pcol) {
  const int b = blockIdx.y;
  const int islab = blockIdx.x;
  const int len0 = lengths[2 * b], len1 = lengths[2 * b + 1];
  const int tid = threadIdx.x;
  const int wave = tid >> 6, lane = tid & 63;
  const int i0 = islab * RPS + wave * 4;
  const int jb = lane * 4;
  const int nrow = min(4, len0 - i0);    // may be <= 0: whole wave masked

  float4 cacc[8];
#pragma unroll
  for (int s = 0; s < 8; ++s) cacc[s] = make_float4(0.f, 0.f, 0.f, 0.f);
  float racc[4] = {0.f, 0.f, 0.f, 0.f};

#pragma unroll
  for (int r = 0; r < 4; ++r) {
    if (r < nrow) {                      // wave-uniform
      const float* p = sim + ((size_t)b * L + (i0 + r)) * L + jb;
      float acc = 0.f;
#pragma unroll
      for (int s = 0; s < 8; ++s) {
        float4 v = *reinterpret_cast<const float4*>(p + s * 256);
        float4 e;
        e.x = fexp2(v.x * C2); e.y = fexp2(v.y * C2);
        e.z = fexp2(v.z * C2); e.w = fexp2(v.w * C2);
        if (s >= 4) {                    // len1 >= 1024: steps 0-3 always valid
          const int j = s * 256 + jb;
          if (j + 0 >= len1) e.x = 0.f;
          if (j + 1 >= len1) e.y = 0.f;
          if (j + 2 >= len1) e.z = 0.f;
          if (j + 3 >= len1) e.w = 0.f;
        }
        acc += (e.x + e.y) + (e.z + e.w);
        cacc[s].x += e.x; cacc[s].y += e.y; cacc[s].z += e.z; cacc[s].w += e.w;
      }
      racc[r] = acc;
    }
  }

  // Deferred butterflies (4 chains overlap); lane0 writes valid rows only.
#pragma unroll
  for (int r = 0; r < 4; ++r) {
    float v = racc[r];
#pragma unroll
    for (int off = 1; off < 64; off <<= 1) v += __shfl_xor(v, off, 64);
    if (lane == 0 && r < nrow) rinv[(size_t)b * L + (i0 + r)] = 1.0f / v;
  }

  __shared__ float cpart[4][2048];       // 32 KB
#pragma unroll
  for (int s = 0; s < 8; ++s)
    *reinterpret_cast<float4*>(&cpart[wave][s * 256 + jb]) = cacc[s];
  __syncthreads();

#pragma unroll
  for (int h = 0; h < 2; ++h) {
    const int c = h * 1024 + tid * 4;
    float4 a0 = *reinterpret_cast<const float4*>(&cpart[0][c]);
    float4 a1 = *reinterpret_cast<const float4*>(&cpart[1][c]);
    float4 a2 = *reinterpret_cast<const float4*>(&cpart[2][c]);
    float4 a3 = *reinterpret_cast<const float4*>(&cpart[3][c]);
    f32x4 o;
    o.x = (a0.x + a1.x) + (a2.x + a3.x);
    o.y = (a0.y + a1.y) + (a2.y + a3.y);
    o.z = (a0.z + a1.z) + (a2.z + a3.z);
    o.w = (a0.w + a1.w) + (a2.w + a3.w);
    __builtin_nontemporal_store(
        o, reinterpret_cast<f32x4*>(&pcol[(size_t)(b * NSPLIT + islab) * L + c]));
  }
}

// Verified round-9 form (dual accumulators, plain loads).
__global__ __launch_bounds__(128) void col_merge_k(
    const float* __restrict__ pcol, float* __restrict__ cinv) {
  const int idx = blockIdx.x * 128 + threadIdx.x;  // b*L + j
  const int b = idx >> 11, j = idx & (L - 1);
  const float* p = pcol + (size_t)b * NSPLIT * L + j;
  float s0 = 0.f, s1 = 0.f;
#pragma unroll 8
  for (int c = 0; c < NSPLIT; c += 2) {
    s0 += p[(size_t)c * L];
    s1 += p[(size_t)(c + 1) * L];
  }
  cinv[idx] = 1.0f / (s0 + s1);   // inf for j >= len1: masked in finalize
}

// Verified round-3/9 structure (one block = one row). NT discipline: sim dead
// after this read -> NT load; out never re-read -> NT store (don't displace
// sim's L3 lines; sim+out = 268MB > 256MB L3).
__global__ __launch_bounds__(512) void finalize_k(
    const float* __restrict__ sim, const int* __restrict__ lengths,
    const float* __restrict__ rinv, const float* __restrict__ cinv,
    float* __restrict__ out) {
  const int row = blockIdx.x;          // b*L + i ; one block = one full row
  const int b = row >> 11, i = row & (L - 1);
  const int len0 = lengths[2 * b], len1 = lengths[2 * b + 1];
  const int j = threadIdx.x * 4;
  const size_t off = (size_t)row * L + j;
  f32x4 o;
  if (i >= len0) {                     // block-uniform branch: zero row
    o = (f32x4){0.f, 0.f, 0.f, 0.f};
  } else {
    const float ri = rinv[row];
    f32x4 v = __builtin_nontemporal_load(
        reinterpret_cast<const f32x4*>(sim + off));
    f32x4 ci = *reinterpret_cast<const f32x4*>(cinv + ((size_t)b << 11) + j);
    o.x = (j + 0 < len1) ? fsqrt(EPSF + fexp2(v.x * C4) * ri * ci.x) : 0.f;
    o.y = (j + 1 < len1) ? fsqrt(EPSF + fexp2(v.y * C4) * ri * ci.y) : 0.f;
    o.z = (j + 2 < len1) ? fsqrt(EPSF + fexp2(v.z * C4) * ri * ci.z) : 0.f;
    o.w = (j + 3 < len1) ? fsqrt(EPSF + fexp2(v.w * C4) * ri * ci.w) : 0.f;
  }
  __builtin_nontemporal_store(o, reinterpret_cast<f32x4*>(out + off));
}

extern "C" void kernel_launch(void* const* d_in, const int* in_sizes, int n_in,
                              void* d_out, int out_size, void* d_ws, size_t ws_size,
                              hipStream_t stream) {
  const float* sim = (const float*)d_in[0];
  const int* lengths = (const int*)d_in[1];
  float* out = (float*)d_out;
  float* ws = (float*)d_ws;

  const int NR = BATCH * L;  // 16384
  float* rinv = ws;
  float* cinv = ws + NR;
  float* pcol = ws + 2 * (size_t)NR;
  // ws use: 2*16384 + 8*128*2048 floats = ~8.1 MiB

  hipLaunchKernelGGL(stats_k, dim3(NSPLIT, BATCH), dim3(256), 0, stream,
                     sim, lengths, rinv, pcol);
  hipLaunchKernelGGL(col_merge_k, dim3(NR / 128), dim3(128), 0, stream,
                     pcol, cinv);
  hipLaunchKernelGGL(finalize_k, dim3(NR), dim3(512), 0, stream,
                     sim, lengths, rinv, cinv, out);
}

// Round 13
// 264.193 us; speedup vs baseline: 1.3881x; 1.0087x over previous
//
#include <hip/hip_runtime.h>
#include <math.h>

#define L 2048
#define BATCH 8
#define RPS 16               // rows per block in stats kernel (4 waves x 4 rows)
#define NSPLIT (L / RPS)     // 128 column-partial slabs per batch
#define EPSF 1e-8f
#define C2 2.885390081777927f   // 2/ln2 : exp(2x) = exp2(x*C2)
#define C4 5.770780163555854f   // 4/ln2 : exp(4x) = exp2(x*C4)

typedef float f32x4 __attribute__((ext_vector_type(4)));
typedef const __attribute__((address_space(1))) void GASV;  // global
typedef __attribute__((address_space(3))) void LASV;        // LDS

__device__ __forceinline__ float fexp2(float x) {
  return __builtin_amdgcn_exp2f(x);   // v_exp_f32
}
__device__ __forceinline__ float fsqrt(float x) {
  return __builtin_amdgcn_sqrtf(x);   // v_sqrt_f32 (~1.5 ulp)
}

// Async-stage one 8KB row (2048 floats) into LDS: 8 x global_load_lds_dwordx4.
// Per-lane SOURCE = rowp + s*256 floats + lane*4 floats; LDS DEST is the
// wave-uniform base + s*1024 bytes (HW adds lane*16). No VGPR destinations ->
// all 8 stay in flight; drained later by a counted s_waitcnt vmcnt(N).
__device__ __forceinline__ void stage_row(const float* rowp, char* dst,
                                          int lane) {
#pragma unroll
  for (int s = 0; s < 8; ++s)
    __builtin_amdgcn_global_load_lds((GASV*)(rowp + s * 256 + lane * 4),
                                     (LASV*)(dst + s * 1024), 16, 0, 0);
}

// 256 threads (4 waves); wave w owns rows i0+4w..+3 (16-row slab per block).
// Rounds 9/11 showed raising the VGPR budget does NOT create memory-level
// parallelism (compiler still consumes each float4 before issuing the next;
// ~1 load in flight -> ~16% HBM, round-5 counters). This version creates MLP
// explicitly with the global_load_lds DMA queue: each wave double-buffers 8KB
// rows in LDS, keeps 8 staged loads in flight across the compute of the
// previous row, and drains with counted vmcnt(8) (never 0 mid-loop).
// LDS: 4 waves x 16KB staging = 64KB, aliased (after barriers) onto the 32KB
// column-partial merge buffer. 2 blocks/CU -> 8 waves/CU x 8KB in flight.
__global__ __launch_bounds__(256) void stats_k(
    const float* __restrict__ sim, const int* __restrict__ lengths,
    float* __restrict__ rinv, float* __restrict__ pcol) {
  const int b = blockIdx.y;
  const int islab = blockIdx.x;
  const int len0 = lengths[2 * b], len1 = lengths[2 * b + 1];
  const int tid = threadIdx.x;
  const int wave = tid >> 6, lane = tid & 63;
  const int i0 = islab * RPS + wave * 4;
  const int jb = lane * 4;
  const int nrow = min(4, len0 - i0);    // may be <= 0: whole wave masked

  __shared__ char arena[65536];          // 64KB: staging, then cpart alias
  char* mybuf = arena + (wave << 14);    // 16KB per wave: two 8KB row buffers

  float4 cacc[8];
#pragma unroll
  for (int s = 0; s < 8; ++s) cacc[s] = make_float4(0.f, 0.f, 0.f, 0.f);
  float racc[4] = {0.f, 0.f, 0.f, 0.f};

  if (nrow > 0) {                        // wave-uniform
    const float* rbase = sim + ((size_t)b * L + i0) * L;
    stage_row(rbase, mybuf, lane);       // prologue: row 0 -> buf 0
#pragma unroll
    for (int r = 0; r < 4; ++r) {
      if (r < nrow) {                    // wave-uniform
        if (r + 1 < nrow) {              // stage next row into other buffer
          stage_row(rbase + (size_t)(r + 1) * L, mybuf + (((r + 1) & 1) << 13),
                    lane);
          asm volatile("s_waitcnt vmcnt(8)" ::: "memory");  // row r resident
        } else {
          asm volatile("s_waitcnt vmcnt(0)" ::: "memory");  // nothing new
        }
        __builtin_amdgcn_sched_barrier(0);
        const char* cb = mybuf + ((r & 1) << 13);
        float acc = 0.f;
#pragma unroll
        for (int s = 0; s < 8; ++s) {
          f32x4 v = *reinterpret_cast<const f32x4*>(cb + s * 1024 + lane * 16);
          float4 e;
          e.x = fexp2(v.x * C2); e.y = fexp2(v.y * C2);
          e.z = fexp2(v.z * C2); e.w = fexp2(v.w * C2);
          if (s >= 4) {                  // len1 >= 1024: steps 0-3 always valid
            const int j = s * 256 + jb;
            if (j + 0 >= len1) e.x = 0.f;
            if (j + 1 >= len1) e.y = 0.f;
            if (j + 2 >= len1) e.z = 0.f;
            if (j + 3 >= len1) e.w = 0.f;
          }
          acc += (e.x + e.y) + (e.z + e.w);
          cacc[s].x += e.x; cacc[s].y += e.y;
          cacc[s].z += e.z; cacc[s].w += e.w;
        }
        racc[r] = acc;
      }
    }
  }
  // All staging DMAs are drained here (each active iteration ended in a
  // counted/zero vmcnt; last active iteration always vmcnt(0)).

  // Deferred butterflies (4 chains overlap); lane0 writes valid rows only.
#pragma unroll
  for (int r = 0; r < 4; ++r) {
    float v = racc[r];
#pragma unroll
    for (int off = 1; off < 64; off <<= 1) v += __shfl_xor(v, off, 64);
    if (lane == 0 && r < nrow) rinv[(size_t)b * L + (i0 + r)] = 1.0f / v;
  }

  __syncthreads();                       // staging regions now dead everywhere
  float* cp = reinterpret_cast<float*>(arena);   // alias: cpart[4][2048] 32KB
#pragma unroll
  for (int s = 0; s < 8; ++s)
    *reinterpret_cast<float4*>(&cp[wave * 2048 + s * 256 + jb]) = cacc[s];
  __syncthreads();

#pragma unroll
  for (int h = 0; h < 2; ++h) {
    const int c = h * 1024 + tid * 4;
    float4 a0 = *reinterpret_cast<const float4*>(&cp[0 * 2048 + c]);
    float4 a1 = *reinterpret_cast<const float4*>(&cp[1 * 2048 + c]);
    float4 a2 = *reinterpret_cast<const float4*>(&cp[2 * 2048 + c]);
    float4 a3 = *reinterpret_cast<const float4*>(&cp[3 * 2048 + c]);
    f32x4 o;
    o.x = (a0.x + a1.x) + (a2.x + a3.x);
    o.y = (a0.y + a1.y) + (a2.y + a3.y);
    o.z = (a0.z + a1.z) + (a2.z + a3.z);
    o.w = (a0.w + a1.w) + (a2.w + a3.w);
    __builtin_nontemporal_store(
        o, reinterpret_cast<f32x4*>(&pcol[(size_t)(b * NSPLIT + islab) * L + c]));
  }
}

// Verified round-9/11 form (dual accumulators, plain loads).
__global__ __launch_bounds__(128) void col_merge_k(
    const float* __restrict__ pcol, float* __restrict__ cinv) {
  const int idx = blockIdx.x * 128 + threadIdx.x;  // b*L + j
  const int b = idx >> 11, j = idx & (L - 1);
  const float* p = pcol + (size_t)b * NSPLIT * L + j;
  float s0 = 0.f, s1 = 0.f;
#pragma unroll 8
  for (int c = 0; c < NSPLIT; c += 2) {
    s0 += p[(size_t)c * L];
    s1 += p[(size_t)(c + 1) * L];
  }
  cinv[idx] = 1.0f / (s0 + s1);   // inf for j >= len1: masked in finalize
}

// Verified round-3/9/11 structure (one block = one row). NT discipline: sim
// dead after this read -> NT load; out never re-read -> NT store (don't
// displace sim's L3 lines; sim+out = 268MB > 256MB L3).
__global__ __launch_bounds__(512) void finalize_k(
    const float* __restrict__ sim, const int* __restrict__ lengths,
    const float* __restrict__ rinv, const float* __restrict__ cinv,
    float* __restrict__ out) {
  const int row = blockIdx.x;          // b*L + i ; one block = one full row
  const int b = row >> 11, i = row & (L - 1);
  const int len0 = lengths[2 * b], len1 = lengths[2 * b + 1];
  const int j = threadIdx.x * 4;
  const size_t off = (size_t)row * L + j;
  f32x4 o;
  if (i >= len0) {                     // block-uniform branch: zero row
    o = (f32x4){0.f, 0.f, 0.f, 0.f};
  } else {
    const float ri = rinv[row];
    f32x4 v = __builtin_nontemporal_load(
        reinterpret_cast<const f32x4*>(sim + off));
    f32x4 ci = *reinterpret_cast<const f32x4*>(cinv + ((size_t)b << 11) + j);
    o.x = (j + 0 < len1) ? fsqrt(EPSF + fexp2(v.x * C4) * ri * ci.x) : 0.f;
    o.y = (j + 1 < len1) ? fsqrt(EPSF + fexp2(v.y * C4) * ri * ci.y) : 0.f;
    o.z = (j + 2 < len1) ? fsqrt(EPSF + fexp2(v.z * C4) * ri * ci.z) : 0.f;
    o.w = (j + 3 < len1) ? fsqrt(EPSF + fexp2(v.w * C4) * ri * ci.w) : 0.f;
  }
  __builtin_nontemporal_store(o, reinterpret_cast<f32x4*>(out + off));
}

extern "C" void kernel_launch(void* const* d_in, const int* in_sizes, int n_in,
                              void* d_out, int out_size, void* d_ws, size_t ws_size,
                              hipStream_t stream) {
  const float* sim = (const float*)d_in[0];
  const int* lengths = (const int*)d_in[1];
  float* out = (float*)d_out;
  float* ws = (float*)d_ws;

  const int NR = BATCH * L;  // 16384
  float* rinv = ws;
  float* cinv = ws + NR;
  float* pcol = ws + 2 * (size_t)NR;
  // ws use: 2*16384 + 8*128*2048 floats = ~8.1 MiB

  hipLaunchKernelGGL(stats_k, dim3(NSPLIT, BATCH), dim3(256), 0, stream,
                     sim, lengths, rinv, pcol);
  hipLaunchKernelGGL(col_merge_k, dim3(NR / 128), dim3(128), 0, stream,
                     pcol, cinv);
  hipLaunchKernelGGL(finalize_k, dim3(NR), dim3(512), 0, stream,
                     sim, lengths, rinv, cinv, out);
}

// Round 14
// 248.063 us; speedup vs baseline: 1.4784x; 1.0650x over previous
//
#include <hip/hip_runtime.h>
#include <math.h>

#define L 2048
#define BATCH 8
#define RPS 16               // rows per block in stats kernel (4 waves x 4 rows)
#define NSPLIT (L / RPS)     // 128 slabs per batch
#define EPSF 1e-8f
#define C2 2.885390081777927f   // 2/ln2 : exp(2x) = exp2(x*C2)
#define C4 5.770780163555854f   // 4/ln2 : exp(4x) = exp2(x*C4)

typedef float f32x4 __attribute__((ext_vector_type(4)));

__device__ __forceinline__ float fexp2(float x) {
  return __builtin_amdgcn_exp2f(x);   // v_exp_f32
}
__device__ __forceinline__ float fsqrt(float x) {
  return __builtin_amdgcn_sqrtf(x);   // v_sqrt_f32 (~1.5 ulp)
}
__device__ __forceinline__ float frcp(float x) {
  return __builtin_amdgcn_rcpf(x);    // v_rcp_f32 (~1 ulp, no div fixup)
}

// Zero the 8x2048 column-sum accumulator (workspace is poisoned by harness).
__global__ __launch_bounds__(512) void zero_k(float* __restrict__ colsum) {
  const int i = (blockIdx.x * 512 + threadIdx.x) * 4;
  *reinterpret_cast<f32x4*>(colsum + i) = (f32x4){0.f, 0.f, 0.f, 0.f};
}

// 256 threads (4 waves); wave w owns rows i0+4w..+3 (verified round-3 inner
// loop). CHANGE vs round 3 (single variable): column partials go straight to
// a global colsum[b][j] via device-scope atomicAdd after the block-local LDS
// merge -- the pcol buffer (8.4MB write + 8.4MB read) and the col_merge
// dispatch are eliminated. 2048 atomics per block, 128 contenders per address
// spread over the kernel: ~10us total. Also pushes this kernel above the
// ~80us fill threshold so rocprof finally reports its counters.
__global__ __launch_bounds__(256) void stats_k(
    const float* __restrict__ sim, const int* __restrict__ lengths,
    float* __restrict__ rinv, float* __restrict__ colsum) {
  const int b = blockIdx.y;
  const int islab = blockIdx.x;
  const int len0 = lengths[2 * b], len1 = lengths[2 * b + 1];
  const int tid = threadIdx.x;
  const int wave = tid >> 6, lane = tid & 63;
  const int i0 = islab * RPS + wave * 4;
  const int jb = lane * 4;
  const int nrow = min(4, len0 - i0);    // may be <= 0: whole wave masked

  float4 cacc[8];
#pragma unroll
  for (int s = 0; s < 8; ++s) cacc[s] = make_float4(0.f, 0.f, 0.f, 0.f);
  float racc[4] = {0.f, 0.f, 0.f, 0.f};

#pragma unroll
  for (int r = 0; r < 4; ++r) {
    if (r < nrow) {                      // wave-uniform
      const float* p = sim + ((size_t)b * L + (i0 + r)) * L + jb;
      float acc = 0.f;
#pragma unroll
      for (int s = 0; s < 8; ++s) {
        float4 v = *reinterpret_cast<const float4*>(p + s * 256);
        float4 e;
        e.x = fexp2(v.x * C2); e.y = fexp2(v.y * C2);
        e.z = fexp2(v.z * C2); e.w = fexp2(v.w * C2);
        if (s >= 4) {                    // len1 >= 1024: steps 0-3 always valid
          const int j = s * 256 + jb;
          if (j + 0 >= len1) e.x = 0.f;
          if (j + 1 >= len1) e.y = 0.f;
          if (j + 2 >= len1) e.z = 0.f;
          if (j + 3 >= len1) e.w = 0.f;
        }
        acc += (e.x + e.y) + (e.z + e.w);
        cacc[s].x += e.x; cacc[s].y += e.y; cacc[s].z += e.z; cacc[s].w += e.w;
      }
      racc[r] = acc;
    }
  }

  // Deferred butterflies (4 chains overlap); lane0 writes valid rows only.
#pragma unroll
  for (int r = 0; r < 4; ++r) {
    float v = racc[r];
#pragma unroll
    for (int off = 1; off < 64; off <<= 1) v += __shfl_xor(v, off, 64);
    if (lane == 0 && r < nrow) rinv[(size_t)b * L + (i0 + r)] = 1.0f / v;
  }

  __shared__ float cpart[4][2048];       // 32 KB
#pragma unroll
  for (int s = 0; s < 8; ++s)
    *reinterpret_cast<float4*>(&cpart[wave][s * 256 + jb]) = cacc[s];
  __syncthreads();

  float* cbase = colsum + ((size_t)b << 11);
#pragma unroll
  for (int h = 0; h < 2; ++h) {
    const int c = h * 1024 + tid * 4;
    float4 a0 = *reinterpret_cast<const float4*>(&cpart[0][c]);
    float4 a1 = *reinterpret_cast<const float4*>(&cpart[1][c]);
    float4 a2 = *reinterpret_cast<const float4*>(&cpart[2][c]);
    float4 a3 = *reinterpret_cast<const float4*>(&cpart[3][c]);
    atomicAdd(cbase + c + 0, (a0.x + a1.x) + (a2.x + a3.x));
    atomicAdd(cbase + c + 1, (a0.y + a1.y) + (a2.y + a3.y));
    atomicAdd(cbase + c + 2, (a0.z + a1.z) + (a2.z + a3.z));
    atomicAdd(cbase + c + 3, (a0.w + a1.w) + (a2.w + a3.w));
  }
}

// Verified round-3 structure (one block = one row). cinv is now colSUM;
// invert inline with v_rcp_f32 (4/thread, ~1.7us chip-wide; rcp(0)=inf for
// masked columns, discarded by the len1 select). NT discipline: sim dead
// after this read -> NT load; out never re-read -> NT store (sim+out =
// 268MB > 256MB L3 -- don't displace sim's lines).
__global__ __launch_bounds__(512) void finalize_k(
    const float* __restrict__ sim, const int* __restrict__ lengths,
    const float* __restrict__ rinv, const float* __restrict__ colsum,
    float* __restrict__ out) {
  const int row = blockIdx.x;          // b*L + i ; one block = one full row
  const int b = row >> 11, i = row & (L - 1);
  const int len0 = lengths[2 * b], len1 = lengths[2 * b + 1];
  const int j = threadIdx.x * 4;
  const size_t off = (size_t)row * L + j;
  f32x4 o;
  if (i >= len0) {                     // block-uniform branch: zero row
    o = (f32x4){0.f, 0.f, 0.f, 0.f};
  } else {
    const float ri = rinv[row];
    f32x4 v = __builtin_nontemporal_load(
        reinterpret_cast<const f32x4*>(sim + off));
    f32x4 cs = *reinterpret_cast<const f32x4*>(colsum + ((size_t)b << 11) + j);
    f32x4 ci;
    ci.x = frcp(cs.x); ci.y = frcp(cs.y);
    ci.z = frcp(cs.z); ci.w = frcp(cs.w);
    o.x = (j + 0 < len1) ? fsqrt(EPSF + fexp2(v.x * C4) * ri * ci.x) : 0.f;
    o.y = (j + 1 < len1) ? fsqrt(EPSF + fexp2(v.y * C4) * ri * ci.y) : 0.f;
    o.z = (j + 2 < len1) ? fsqrt(EPSF + fexp2(v.z * C4) * ri * ci.z) : 0.f;
    o.w = (j + 3 < len1) ? fsqrt(EPSF + fexp2(v.w * C4) * ri * ci.w) : 0.f;
  }
  __builtin_nontemporal_store(o, reinterpret_cast<f32x4*>(out + off));
}

extern "C" void kernel_launch(void* const* d_in, const int* in_sizes, int n_in,
                              void* d_out, int out_size, void* d_ws, size_t ws_size,
                              hipStream_t stream) {
  const float* sim = (const float*)d_in[0];
  const int* lengths = (const int*)d_in[1];
  float* out = (float*)d_out;
  float* ws = (float*)d_ws;

  const int NR = BATCH * L;  // 16384
  float* rinv = ws;
  float* colsum = ws + NR;
  // ws use: 2*16384 floats = 128 KB (pcol eliminated)

  hipLaunchKernelGGL(zero_k, dim3(NR / 2048), dim3(512), 0, stream, colsum);
  hipLaunchKernelGGL(stats_k, dim3(NSPLIT, BATCH), dim3(256), 0, stream,
                     sim, lengths, rinv, colsum);
  hipLaunchKernelGGL(finalize_k, dim3(NR), dim3(512), 0, stream,
                     sim, lengths, rinv, colsum, out);
}